// Round 1
// baseline (892.746 us; speedup 1.0000x reference)
//
#include <hip/hip_runtime.h>
#include <cstddef>
#include <cstdint>

#define IN_C   512
#define HID    64
#define OUTC   40
#define HEADS  4
#define NEG    0.2f
#define EPSV   1e-16f

__device__ __forceinline__ float waveSum(float v) {
#pragma unroll
  for (int off = 32; off; off >>= 1) v += __shfl_xor(v, off, 64);
  return v;
}
__device__ __forceinline__ float waveMax(float v) {
#pragma unroll
  for (int off = 32; off; off >>= 1) v = fmaxf(v, __shfl_xor(v, off, 64));
  return v;
}

// ---------------- CSR build ----------------
__global__ void hist_k(const int* __restrict__ dst, int* __restrict__ cnt, int E) {
  int e = blockIdx.x * blockDim.x + threadIdx.x;
  if (e < E) atomicAdd(&cnt[dst[e]], 1);
}

// single-block exclusive scan of cnt[0..n) -> rp[0..n]
__global__ __launch_bounds__(1024) void scan_k(const int* __restrict__ cnt,
                                               int* __restrict__ rp, int n) {
  __shared__ int part[1024];
  const int tid = threadIdx.x;
  const int chunk = (n + 1023) / 1024;
  const int base = tid * chunk;
  int s = 0;
  for (int k = 0; k < chunk; ++k) { int i = base + k; if (i < n) s += cnt[i]; }
  part[tid] = s;
  __syncthreads();
  for (int d = 1; d < 1024; d <<= 1) {
    int t = (tid >= d) ? part[tid - d] : 0;
    __syncthreads();
    part[tid] += t;
    __syncthreads();
  }
  int run = part[tid] - s;  // exclusive prefix
  for (int k = 0; k < chunk; ++k) {
    int i = base + k;
    if (i < n) { rp[i] = run; run += cnt[i]; }
  }
  if (tid == 0) rp[n] = part[1023];
}

__global__ void scatter_k(const int* __restrict__ src, const int* __restrict__ dst,
                          const int* __restrict__ rp, int* __restrict__ cur,
                          int* __restrict__ out, int E) {
  int e = blockIdx.x * blockDim.x + threadIdx.x;
  if (e < E) {
    int d = dst[e];
    int p = rp[d] + atomicAdd(&cur[d], 1);
    out[p] = src[e];
  }
}

// ---------------- fp32 tiled GEMM (vector ALU; no fp32 MFMA on CDNA4) ----------------
// C[M,Nc] = A[M,K] @ B[K,Nc], row-major. Requires Nc % BN == 0, K % BK == 0.
template <int BM, int BN, int BK, int TM, int TN>
__global__ __launch_bounds__(256) void gemm_f32(const float* __restrict__ A,
                                                const float* __restrict__ B,
                                                float* __restrict__ C,
                                                int M, int Nc, int K) {
  __shared__ float As[BK][BM + 4];
  __shared__ float Bs[BK][BN + 4];
  const int tid = threadIdx.x;
  const int tx = tid % (BN / TN);
  const int ty = tid / (BN / TN);
  const int row0 = blockIdx.y * BM;
  const int col0 = blockIdx.x * BN;
  float acc[TM][TN] = {};

  for (int k0 = 0; k0 < K; k0 += BK) {
    // A tile: BM x BK, loaded as float4 along K, stored transposed.
    constexpr int A_F4 = BM * BK / 4;
#pragma unroll
    for (int it = 0; it < (A_F4 + 255) / 256; ++it) {
      int idx = tid + it * 256;
      if (idx < A_F4) {
        int ar = idx / (BK / 4);
        int ac4 = idx % (BK / 4);
        float4 v = make_float4(0.f, 0.f, 0.f, 0.f);
        int grow = row0 + ar;
        if (grow < M) v = *(const float4*)&A[(size_t)grow * K + k0 + ac4 * 4];
        As[ac4 * 4 + 0][ar] = v.x;
        As[ac4 * 4 + 1][ar] = v.y;
        As[ac4 * 4 + 2][ar] = v.z;
        As[ac4 * 4 + 3][ar] = v.w;
      }
    }
    // B tile: BK x BN, float4 rows. (Nc multiple of BN -> no col guard.)
    constexpr int B_F4 = BK * BN / 4;
#pragma unroll
    for (int it = 0; it < (B_F4 + 255) / 256; ++it) {
      int idx = tid + it * 256;
      if (idx < B_F4) {
        int br = idx / (BN / 4);
        int bc4 = idx % (BN / 4);
        *(float4*)&Bs[br][bc4 * 4] =
            *(const float4*)&B[(size_t)(k0 + br) * Nc + col0 + bc4 * 4];
      }
    }
    __syncthreads();
#pragma unroll
    for (int kk = 0; kk < BK; ++kk) {
      float a[TM], b[TN];
#pragma unroll
      for (int m = 0; m < TM; ++m) a[m] = As[kk][ty * TM + m];
#pragma unroll
      for (int n = 0; n < TN; ++n) b[n] = Bs[kk][tx * TN + n];
#pragma unroll
      for (int m = 0; m < TM; ++m)
#pragma unroll
        for (int n = 0; n < TN; ++n) acc[m][n] += a[m] * b[n];
    }
    __syncthreads();
  }
#pragma unroll
  for (int m = 0; m < TM; ++m) {
    int grow = row0 + ty * TM + m;
    if (grow < M) {
#pragma unroll
      for (int n = 0; n < TN; ++n)
        C[(size_t)grow * Nc + col0 + tx * TN + n] = acc[m][n];
    }
  }
}

// ---------------- layer-1 attention aggregation (block=node, wave=head, lane=channel) ----------------
__global__ __launch_bounds__(256) void agg1_k(const float* __restrict__ h,
                                              const int* __restrict__ rp,
                                              const int* __restrict__ srt,
                                              const float* __restrict__ b1,
                                              float* __restrict__ out) {
  const int node = blockIdx.x;
  const int head = threadIdx.x >> 6;
  const int lane = threadIdx.x & 63;
  const int base = node * (HEADS * HID) + head * HID + lane;
  const float xi = h[base];
  // self-loop (always present exactly once)
  float a = waveSum(xi * xi);
  a = a > 0.f ? a : NEG * a;
  float m = a, l = 1.f, acc = xi;  // exp(a - a) = 1
  const int e0 = rp[node], e1 = rp[node + 1];
  for (int e = e0; e < e1; ++e) {
    int s = srt[e];
    float xj = h[s * (HEADS * HID) + head * HID + lane];
    float al = waveSum(xi * xj);
    al = al > 0.f ? al : NEG * al;
    if (al > m) {                       // wave-uniform branch
      float sc = __expf(m - al);
      l *= sc; acc *= sc; m = al;
    }
    float w = __expf(al - m);
    l += w; acc += w * xj;
  }
  float o = acc / (l + EPSV) + b1[head * HID + lane];
  o = o > 0.f ? o : __expf(o) - 1.f;    // ELU
  out[base] = o;
}

// ---------------- layer-2 aggregation + head-mean + b2 + log_softmax ----------------
__global__ __launch_bounds__(256) void agg2_k(const float* __restrict__ h,
                                              const int* __restrict__ rp,
                                              const int* __restrict__ srt,
                                              const float* __restrict__ b2,
                                              float* __restrict__ out, int Nn) {
  __shared__ float hd[HEADS][OUTC];
  const int node = blockIdx.x;
  const int head = threadIdx.x >> 6;
  const int lane = threadIdx.x & 63;
  const bool act = lane < OUTC;
  const int rowb = node * (HEADS * OUTC) + head * OUTC;
  const float xi = act ? h[rowb + lane] : 0.f;
  float a = waveSum(xi * xi);
  a = a > 0.f ? a : NEG * a;
  float m = a, l = 1.f, acc = xi;
  const int e0 = rp[node], e1 = rp[node + 1];
  for (int e = e0; e < e1; ++e) {
    int s = srt[e];
    float xj = act ? h[s * (HEADS * OUTC) + head * OUTC + lane] : 0.f;
    float al = waveSum(xi * xj);
    al = al > 0.f ? al : NEG * al;
    if (al > m) {
      float sc = __expf(m - al);
      l *= sc; acc *= sc; m = al;
    }
    float w = __expf(al - m);
    l += w; acc += w * xj;
  }
  if (act) hd[head][lane] = acc / (l + EPSV);
  __syncthreads();
  if (threadIdx.x < 64) {
    int c = threadIdx.x;
    float v = (c < OUTC)
                  ? 0.25f * (hd[0][c] + hd[1][c] + hd[2][c] + hd[3][c]) + b2[c]
                  : -1e30f;
    float mx = waveMax(v);
    float ex = (c < OUTC) ? __expf(v - mx) : 0.f;
    float s = waveSum(ex);
    float lse = mx + __logf(s);
    if (c < OUTC) out[(size_t)node * OUTC + c] = v - lse;
  }
  if (node == 0 && threadIdx.x == 0) out[(size_t)Nn * OUTC] = 0.f;  // att_loss
}

extern "C" void kernel_launch(void* const* d_in, const int* in_sizes, int n_in,
                              void* d_out, int out_size, void* d_ws, size_t ws_size,
                              hipStream_t stream) {
  const float* x  = (const float*)d_in[0];
  const int*   ei = (const int*)d_in[1];
  const float* W1 = (const float*)d_in[2];
  const float* b1 = (const float*)d_in[3];
  const float* W2 = (const float*)d_in[4];
  const float* b2 = (const float*)d_in[5];
  float* out = (float*)d_out;

  const int Nn = in_sizes[0] / IN_C;  // 50000
  const int E  = in_sizes[1] / 2;     // 400000
  const int* esrc = ei;
  const int* edst = ei + E;

  // workspace layout (16B aligned)
  char* ws = (char*)d_ws;
  const size_t szH = (size_t)Nn * (HEADS * HID) * sizeof(float);  // 51.2 MB
  float* h1 = (float*)(ws);            // GEMM1 out [N,256]; later reused as h2 [N,160]
  float* g1 = (float*)(ws + szH);      // layer-1 output (post-ELU) [N,256]
  size_t off = 2 * szH;
  int* rp = (int*)(ws + off);          // N+1
  off += ((size_t)(Nn + 1) * 4 + 15) & ~(size_t)15;
  int* cnt = (int*)(ws + off);         // N
  off += ((size_t)Nn * 4 + 15) & ~(size_t)15;
  int* srt = (int*)(ws + off);         // E  (src sorted by dst)
  float* h2 = h1;

  // CSR by destination (rebuilt every call; ws is re-poisoned)
  hipMemsetAsync(cnt, 0, (size_t)Nn * sizeof(int), stream);
  hist_k<<<(E + 255) / 256, 256, 0, stream>>>(edst, cnt, E);
  scan_k<<<1, 1024, 0, stream>>>(cnt, rp, Nn);
  hipMemsetAsync(cnt, 0, (size_t)Nn * sizeof(int), stream);
  scatter_k<<<(E + 255) / 256, 256, 0, stream>>>(esrc, edst, rp, cnt, srt, E);

  // layer 1: h1 = x @ W1   [50000,512]x[512,256]
  gemm_f32<128, 128, 16, 8, 8>
      <<<dim3(256 / 128, (Nn + 127) / 128), 256, 0, stream>>>(x, W1, h1, Nn, 256, 512);
  agg1_k<<<Nn, 256, 0, stream>>>(h1, rp, srt, b1, g1);

  // layer 2: h2 = g1 @ W2  [50000,256]x[256,160]
  gemm_f32<128, 32, 16, 8, 2>
      <<<dim3(160 / 32, (Nn + 127) / 128), 256, 0, stream>>>(g1, W2, h2, Nn, 160, 256);
  agg2_k<<<Nn, 256, 0, stream>>>(h2, rp, srt, b2, out, Nn);
}

// Round 2
// 508.195 us; speedup vs baseline: 1.7567x; 1.7567x over previous
//
#include <hip/hip_runtime.h>
#include <cstddef>
#include <cstdint>

#define HEADS 4
#define OUTC  40
#define NEG   0.2f
#define EPSV  1e-16f

typedef __bf16 bf16x8 __attribute__((ext_vector_type(8)));
typedef float  floatx4 __attribute__((ext_vector_type(4)));

__device__ __forceinline__ void split_bf16(float a, unsigned& hi, unsigned& lo) {
  unsigned u = __float_as_uint(a);
  hi = u >> 16;                                   // RTZ high bf16
  float hf = __uint_as_float(u & 0xFFFF0000u);
  lo = __float_as_uint(a - hf) >> 16;             // RTZ residual bf16
}

// ---------------- CSR build ----------------
__global__ void hist_k(const int* __restrict__ dst, int* __restrict__ cnt, int E) {
  int e = blockIdx.x * blockDim.x + threadIdx.x;
  if (e < E) atomicAdd(&cnt[dst[e]], 1);
}

__global__ __launch_bounds__(1024) void scanA_k(const int* __restrict__ cnt,
                                                int* __restrict__ rp,
                                                int* __restrict__ bsum, int n) {
  __shared__ int sh[1024];
  int i = blockIdx.x * 1024 + threadIdx.x;
  int v = (i < n) ? cnt[i] : 0;
  sh[threadIdx.x] = v;
  __syncthreads();
  for (int d = 1; d < 1024; d <<= 1) {
    int t = (threadIdx.x >= d) ? sh[threadIdx.x - d] : 0;
    __syncthreads();
    sh[threadIdx.x] += t;
    __syncthreads();
  }
  if (i < n) rp[i] = sh[threadIdx.x] - v;  // block-local exclusive
  if (threadIdx.x == 1023) bsum[blockIdx.x] = sh[1023];
}

__global__ void scanB_k(const int* __restrict__ bsum, int* __restrict__ boff, int nb) {
  if (blockIdx.x == 0 && threadIdx.x == 0) {
    int run = 0;
    for (int b = 0; b < nb; ++b) { boff[b] = run; run += bsum[b]; }
    boff[nb] = run;
  }
}

__global__ void scanC_k(int* __restrict__ rp, const int* __restrict__ boff, int n) {
  int i = blockIdx.x * blockDim.x + threadIdx.x;
  if (i < n) rp[i] += boff[i >> 10];
  if (i == 0) rp[n] = boff[(n + 1023) >> 10];
}

__global__ void scatter_k(const int* __restrict__ src, const int* __restrict__ dst,
                          const int* __restrict__ rp, int* __restrict__ cur,
                          int* __restrict__ out, int E) {
  int e = blockIdx.x * blockDim.x + threadIdx.x;
  if (e < E) {
    int d = dst[e];
    int p = rp[d] + atomicAdd(&cur[d], 1);
    out[p] = src[e];
  }
}

// ---------------- weight pre-split: W [K,Nc] fp32 -> Wh/Wl [256][K] bf16 ----------------
__global__ void convW1_k(const float* __restrict__ W, unsigned short* __restrict__ Wh,
                         unsigned short* __restrict__ Wl) {
  int id = blockIdx.x * 256 + threadIdx.x;  // 256*512
  int n = id >> 9, k = id & 511;
  unsigned h, l;
  split_bf16(W[k * 256 + n], h, l);
  Wh[id] = (unsigned short)h;
  Wl[id] = (unsigned short)l;
}

__global__ void convW2_k(const float* __restrict__ W, unsigned short* __restrict__ Wh,
                         unsigned short* __restrict__ Wl) {
  int id = blockIdx.x * 256 + threadIdx.x;  // 256*256, cols padded 160->256
  int n = id >> 8, k = id & 255;
  int hh = n >> 6, c = n & 63;
  float a = (c < OUTC) ? W[k * 160 + hh * OUTC + c] : 0.f;
  unsigned h, l;
  split_bf16(a, h, l);
  Wh[id] = (unsigned short)h;
  Wl[id] = (unsigned short)l;
}

// ---------------- split-bf16 MFMA GEMM: C[M,256] = A[M,K] @ B[K,256] ----------------
// A fp32 (split in-kernel). B pre-split bf16 in [n][K] layout. Tile 128x128, BK=32.
__global__ __launch_bounds__(256) void gemm_split(const float* __restrict__ A,
                                                  const unsigned short* __restrict__ Bh,
                                                  const unsigned short* __restrict__ Bl,
                                                  float* __restrict__ C, int M, int K) {
  __shared__ unsigned short Ah[128][40], Al[128][40], Bhs[128][40], Bls[128][40];
  const int tid = threadIdx.x;
  const int lane = tid & 63;
  const int w = tid >> 6;
  const int wr = w >> 1, wc = w & 1;
  const int row0 = blockIdx.y * 128;
  const int col0 = blockIdx.x * 128;
  const int fr = lane & 15, fq = lane >> 4;

  floatx4 acc[4][4];
#pragma unroll
  for (int i = 0; i < 4; ++i)
#pragma unroll
    for (int j = 0; j < 4; ++j) acc[i][j] = (floatx4){0.f, 0.f, 0.f, 0.f};

  for (int k0 = 0; k0 < K; k0 += 32) {
    // stage A: 128x32 fp32 -> hi/lo bf16
#pragma unroll
    for (int t = 0; t < 4; ++t) {
      int idx = tid + t * 256;
      int m = idx >> 3, ks = idx & 7;
      int gr = row0 + m;
      float4 v = make_float4(0.f, 0.f, 0.f, 0.f);
      if (gr < M) v = *(const float4*)&A[(size_t)gr * K + k0 + ks * 4];
      unsigned h0, l0, h1, l1, h2, l2, h3, l3;
      split_bf16(v.x, h0, l0);
      split_bf16(v.y, h1, l1);
      split_bf16(v.z, h2, l2);
      split_bf16(v.w, h3, l3);
      *(uint2*)&Ah[m][ks * 4] = make_uint2(h0 | (h1 << 16), h2 | (h3 << 16));
      *(uint2*)&Al[m][ks * 4] = make_uint2(l0 | (l1 << 16), l2 | (l3 << 16));
    }
    // stage B: pre-split bf16, [n][K] rows
#pragma unroll
    for (int t = 0; t < 2; ++t) {
      int idx = tid + t * 256;
      int n = idx >> 2, ks = idx & 3;
      size_t g = (size_t)(col0 + n) * K + k0 + ks * 8;
      uint4 vh = *(const uint4*)&Bh[g];
      uint4 vl = *(const uint4*)&Bl[g];
      *(uint4*)&Bhs[n][ks * 8] = vh;
      *(uint4*)&Bls[n][ks * 8] = vl;
    }
    __syncthreads();

    bf16x8 ah[4], al[4], bh[4], bl[4];
#pragma unroll
    for (int i = 0; i < 4; ++i) {
      ah[i] = *(bf16x8*)&Ah[wr * 64 + i * 16 + fr][fq * 8];
      al[i] = *(bf16x8*)&Al[wr * 64 + i * 16 + fr][fq * 8];
      bh[i] = *(bf16x8*)&Bhs[wc * 64 + i * 16 + fr][fq * 8];
      bl[i] = *(bf16x8*)&Bls[wc * 64 + i * 16 + fr][fq * 8];
    }
#pragma unroll
    for (int i = 0; i < 4; ++i)
#pragma unroll
      for (int j = 0; j < 4; ++j) {
        acc[i][j] = __builtin_amdgcn_mfma_f32_16x16x32_bf16(ah[i], bh[j], acc[i][j], 0, 0, 0);
        acc[i][j] = __builtin_amdgcn_mfma_f32_16x16x32_bf16(ah[i], bl[j], acc[i][j], 0, 0, 0);
        acc[i][j] = __builtin_amdgcn_mfma_f32_16x16x32_bf16(al[i], bh[j], acc[i][j], 0, 0, 0);
      }
    __syncthreads();
  }

  // epilogue: C/D layout col=lane&15, row=(lane>>4)*4+r  [m89]
#pragma unroll
  for (int i = 0; i < 4; ++i) {
    int grow_base = row0 + wr * 64 + i * 16 + fq * 4;
#pragma unroll
    for (int r = 0; r < 4; ++r) {
      int grow = grow_base + r;
      if (grow < M) {
#pragma unroll
        for (int j = 0; j < 4; ++j)
          C[(size_t)grow * 256 + col0 + wc * 64 + j * 16 + fr] = acc[i][j][r];
      }
    }
  }
}

// ---------------- layer-1 agg: wave per node, lane = (head, 4 channels) ----------------
__global__ __launch_bounds__(256) void agg1_k(const float* __restrict__ h,
                                              const int* __restrict__ rp,
                                              const int* __restrict__ srt,
                                              const float* __restrict__ b1,
                                              float* __restrict__ out, int Nn) {
  int wv = threadIdx.x >> 6, lane = threadIdx.x & 63;
  int node = blockIdx.x * 4 + wv;
  if (node >= Nn) node = Nn - 1;
  const float4 xi = *(const float4*)&h[(size_t)node * 256 + lane * 4];
  float p = xi.x * xi.x + xi.y * xi.y + xi.z * xi.z + xi.w * xi.w;
  p += __shfl_xor(p, 1); p += __shfl_xor(p, 2); p += __shfl_xor(p, 4); p += __shfl_xor(p, 8);
  float a = p > 0.f ? p : NEG * p;      // self-loop logit
  float m = a, l = 1.f;
  float4 acc = xi;
  const int e0 = rp[node], e1 = rp[node + 1];
  for (int e = e0; e < e1; ++e) {
    int s = srt[e];
    const float4 xj = *(const float4*)&h[(size_t)s * 256 + lane * 4];
    float q = xi.x * xj.x + xi.y * xj.y + xi.z * xj.z + xi.w * xj.w;
    q += __shfl_xor(q, 1); q += __shfl_xor(q, 2); q += __shfl_xor(q, 4); q += __shfl_xor(q, 8);
    float al = q > 0.f ? q : NEG * q;
    float nm = fmaxf(m, al);
    float sc = __expf(m - nm), wt = __expf(al - nm);
    l = l * sc + wt;
    acc.x = acc.x * sc + wt * xj.x;
    acc.y = acc.y * sc + wt * xj.y;
    acc.z = acc.z * sc + wt * xj.z;
    acc.w = acc.w * sc + wt * xj.w;
    m = nm;
  }
  float inv = 1.f / (l + EPSV);
  const float4 bb = *(const float4*)&b1[lane * 4];
  float4 o;
  o.x = acc.x * inv + bb.x;
  o.y = acc.y * inv + bb.y;
  o.z = acc.z * inv + bb.z;
  o.w = acc.w * inv + bb.w;
  o.x = o.x > 0.f ? o.x : __expf(o.x) - 1.f;
  o.y = o.y > 0.f ? o.y : __expf(o.y) - 1.f;
  o.z = o.z > 0.f ? o.z : __expf(o.z) - 1.f;
  o.w = o.w > 0.f ? o.w : __expf(o.w) - 1.f;
  *(float4*)&out[(size_t)node * 256 + lane * 4] = o;
}

// ---------------- layer-2 agg + head-mean + b2 + log_softmax ----------------
__global__ __launch_bounds__(256) void agg2_k(const float* __restrict__ h,
                                              const int* __restrict__ rp,
                                              const int* __restrict__ srt,
                                              const float* __restrict__ b2,
                                              float* __restrict__ out, int Nn) {
  __shared__ float buf[4][256];
  int wv = threadIdx.x >> 6, lane = threadIdx.x & 63;
  int node = blockIdx.x * 4 + wv;
  if (node >= Nn) node = Nn - 1;
  const float4 xi = *(const float4*)&h[(size_t)node * 256 + lane * 4];
  float p = xi.x * xi.x + xi.y * xi.y + xi.z * xi.z + xi.w * xi.w;
  p += __shfl_xor(p, 1); p += __shfl_xor(p, 2); p += __shfl_xor(p, 4); p += __shfl_xor(p, 8);
  float a = p > 0.f ? p : NEG * p;
  float m = a, l = 1.f;
  float4 acc = xi;
  const int e0 = rp[node], e1 = rp[node + 1];
  for (int e = e0; e < e1; ++e) {
    int s = srt[e];
    const float4 xj = *(const float4*)&h[(size_t)s * 256 + lane * 4];
    float q = xi.x * xj.x + xi.y * xj.y + xi.z * xj.z + xi.w * xj.w;
    q += __shfl_xor(q, 1); q += __shfl_xor(q, 2); q += __shfl_xor(q, 4); q += __shfl_xor(q, 8);
    float al = q > 0.f ? q : NEG * q;
    float nm = fmaxf(m, al);
    float sc = __expf(m - nm), wt = __expf(al - nm);
    l = l * sc + wt;
    acc.x = acc.x * sc + wt * xj.x;
    acc.y = acc.y * sc + wt * xj.y;
    acc.z = acc.z * sc + wt * xj.z;
    acc.w = acc.w * sc + wt * xj.w;
    m = nm;
  }
  float inv = 1.f / (l + EPSV);
  float4 res;
  res.x = acc.x * inv; res.y = acc.y * inv; res.z = acc.z * inv; res.w = acc.w * inv;
  *(float4*)&buf[wv][lane * 4] = res;   // buf[wv][h*64 + c]
  __syncthreads();
  float v = 0.f;
  if (lane < OUTC)
    v = 0.25f * (buf[wv][lane] + buf[wv][64 + lane] + buf[wv][128 + lane] + buf[wv][192 + lane]) +
        b2[lane];
  float t = (lane < OUTC) ? v : -1e30f;
#pragma unroll
  for (int off = 32; off; off >>= 1) t = fmaxf(t, __shfl_xor(t, off));
  float ex = (lane < OUTC) ? __expf(v - t) : 0.f;
  float s = ex;
#pragma unroll
  for (int off = 32; off; off >>= 1) s += __shfl_xor(s, off);
  float lse = t + __logf(s);
  if (lane < OUTC) out[(size_t)node * OUTC + lane] = v - lse;
  if (blockIdx.x == 0 && threadIdx.x == 0) out[(size_t)Nn * OUTC] = 0.f;  // att_loss
}

extern "C" void kernel_launch(void* const* d_in, const int* in_sizes, int n_in,
                              void* d_out, int out_size, void* d_ws, size_t ws_size,
                              hipStream_t stream) {
  const float* x  = (const float*)d_in[0];
  const int*   ei = (const int*)d_in[1];
  const float* W1 = (const float*)d_in[2];
  const float* b1 = (const float*)d_in[3];
  const float* W2 = (const float*)d_in[4];
  const float* b2 = (const float*)d_in[5];
  float* out = (float*)d_out;

  const int Nn = in_sizes[0] / 512;  // 50000
  const int E  = in_sizes[1] / 2;    // 400000
  const int* esrc = ei;
  const int* edst = ei + E;
  const int NB = (Nn + 1023) / 1024;  // scan blocks

  // workspace layout
  char* ws = (char*)d_ws;
  const size_t szH = (size_t)Nn * 256 * sizeof(float);  // 51.2 MB
  float* h1 = (float*)(ws);           // GEMM1 out; reused as h2
  float* g1 = (float*)(ws + szH);     // layer-1 activations
  size_t off = 2 * szH;
  int* rp = (int*)(ws + off);   off += ((size_t)(Nn + 1) * 4 + 15) & ~(size_t)15;
  int* cnt = (int*)(ws + off);  off += ((size_t)Nn * 4 + 15) & ~(size_t)15;
  int* srt = (int*)(ws + off);  off += ((size_t)E * 4 + 15) & ~(size_t)15;
  int* bsum = (int*)(ws + off); off += 1024;
  int* boff = (int*)(ws + off); off += 1024;
  unsigned short* Wh1 = (unsigned short*)(ws + off); off += (size_t)256 * 512 * 2;
  unsigned short* Wl1 = (unsigned short*)(ws + off); off += (size_t)256 * 512 * 2;
  unsigned short* Wh2 = (unsigned short*)(ws + off); off += (size_t)256 * 256 * 2;
  unsigned short* Wl2 = (unsigned short*)(ws + off); off += (size_t)256 * 256 * 2;
  float* h2 = h1;

  // CSR by destination
  hipMemsetAsync(cnt, 0, (size_t)Nn * sizeof(int), stream);
  hist_k<<<(E + 255) / 256, 256, 0, stream>>>(edst, cnt, E);
  scanA_k<<<NB, 1024, 0, stream>>>(cnt, rp, bsum, Nn);
  scanB_k<<<1, 64, 0, stream>>>(bsum, boff, NB);
  scanC_k<<<(Nn + 255) / 256, 256, 0, stream>>>(rp, boff, Nn);
  hipMemsetAsync(cnt, 0, (size_t)Nn * sizeof(int), stream);
  scatter_k<<<(E + 255) / 256, 256, 0, stream>>>(esrc, edst, rp, cnt, srt, E);

  // weight pre-split
  convW1_k<<<512, 256, 0, stream>>>(W1, Wh1, Wl1);
  convW2_k<<<256, 256, 0, stream>>>(W2, Wh2, Wl2);

  // layer 1
  gemm_split<<<dim3(2, (Nn + 127) / 128), 256, 0, stream>>>(x, Wh1, Wl1, h1, Nn, 512);
  agg1_k<<<(Nn + 3) / 4, 256, 0, stream>>>(h1, rp, srt, b1, g1, Nn);

  // layer 2 (output padded [N,4,64])
  gemm_split<<<dim3(2, (Nn + 127) / 128), 256, 0, stream>>>(g1, Wh2, Wl2, h2, Nn, 256);
  agg2_k<<<(Nn + 3) / 4, 256, 0, stream>>>(h2, rp, srt, b2, out, Nn);
}